// Round 1
// baseline (2074.060 us; speedup 1.0000x reference)
//
#include <hip/hip_runtime.h>
#include <math.h>

#define NNB   32
#define NDIM  128
#define NHEAD 8
#define LPAD  (NDIM + 2)   // LDS row stride (floats): breaks bank conflicts, keeps 8B align

__device__ __forceinline__ float elu_f(float v) {
    return v > 0.0f ? v : (__expf(v) - 1.0f);
}

// ---------------------------------------------------------------------------
// Kernel 1: Q = elu(F @ qW1 + qb1) @ qW2 + qb2      (N,128) -> (N,1024)
// ---------------------------------------------------------------------------
__global__ __launch_bounds__(256) void qmlp_kernel(
    const float* __restrict__ F,
    const float* __restrict__ W1, const float* __restrict__ b1,
    const float* __restrict__ W2, const float* __restrict__ b2,
    float* __restrict__ Q, int n)
{
    __shared__ float sIn[64][NDIM];
    __shared__ float sH[64][NDIM];
    const int t = threadIdx.x;
    const int row0 = blockIdx.x * 64;

    for (int i = t; i < 64 * (NDIM / 4); i += 256) {
        int r = i >> 5;
        int c4 = (i & 31) * 4;
        int gr = row0 + r;
        float4 v = make_float4(0.f, 0.f, 0.f, 0.f);
        if (gr < n) v = *(const float4*)&F[(size_t)gr * NDIM + c4];
        *(float4*)&sIn[r][c4] = v;
    }
    __syncthreads();

    const int cg = t & 31, rg = t >> 5;
    const int c0 = cg * 4;

    // layer 1: 128 -> 128, elu
    {
        float acc[8][4];
        #pragma unroll
        for (int r = 0; r < 8; r++)
            for (int c = 0; c < 4; c++) acc[r][c] = 0.f;
        #pragma unroll 2
        for (int j = 0; j < NDIM; j += 2) {
            float4 w0 = *(const float4*)&W1[j * NDIM + c0];
            float4 w1 = *(const float4*)&W1[(j + 1) * NDIM + c0];
            #pragma unroll
            for (int r = 0; r < 8; r++) {
                float2 a = *(const float2*)&sIn[rg * 8 + r][j];
                acc[r][0] += a.x * w0.x; acc[r][1] += a.x * w0.y;
                acc[r][2] += a.x * w0.z; acc[r][3] += a.x * w0.w;
                acc[r][0] += a.y * w1.x; acc[r][1] += a.y * w1.y;
                acc[r][2] += a.y * w1.z; acc[r][3] += a.y * w1.w;
            }
        }
        float4 bv = *(const float4*)&b1[c0];
        #pragma unroll
        for (int r = 0; r < 8; r++) {
            sH[rg * 8 + r][c0 + 0] = elu_f(acc[r][0] + bv.x);
            sH[rg * 8 + r][c0 + 1] = elu_f(acc[r][1] + bv.y);
            sH[rg * 8 + r][c0 + 2] = elu_f(acc[r][2] + bv.z);
            sH[rg * 8 + r][c0 + 3] = elu_f(acc[r][3] + bv.w);
        }
    }
    __syncthreads();

    // layer 2: 128 -> 1024, no activation
    for (int ct = 0; ct < 8; ct++) {
        float acc[8][4];
        #pragma unroll
        for (int r = 0; r < 8; r++)
            for (int c = 0; c < 4; c++) acc[r][c] = 0.f;
        const int cc0 = ct * 128 + c0;
        #pragma unroll 2
        for (int j = 0; j < NDIM; j += 2) {
            float4 w0 = *(const float4*)&W2[j * 1024 + cc0];
            float4 w1 = *(const float4*)&W2[(j + 1) * 1024 + cc0];
            #pragma unroll
            for (int r = 0; r < 8; r++) {
                float2 a = *(const float2*)&sH[rg * 8 + r][j];
                acc[r][0] += a.x * w0.x; acc[r][1] += a.x * w0.y;
                acc[r][2] += a.x * w0.z; acc[r][3] += a.x * w0.w;
                acc[r][0] += a.y * w1.x; acc[r][1] += a.y * w1.y;
                acc[r][2] += a.y * w1.z; acc[r][3] += a.y * w1.w;
            }
        }
        float4 bv = *(const float4*)&b2[cc0];
        #pragma unroll
        for (int r = 0; r < 8; r++) {
            int gr = row0 + rg * 8 + r;
            if (gr < n) {
                float4 o = make_float4(acc[r][0] + bv.x, acc[r][1] + bv.y,
                                       acc[r][2] + bv.z, acc[r][3] + bv.w);
                *(float4*)&Q[(size_t)gr * 1024 + cc0] = o;
            }
        }
    }
}

// ---------------------------------------------------------------------------
// Kernel 2: fused per-point geometry + geo/K/V MLPs + attention
// one block (256 threads) per point
// ---------------------------------------------------------------------------

// acc[4][4] += in[rg*4 .. rg*4+3][:] @ W[:, c0..c0+3]   (K = 128)
__device__ __forceinline__ void mm32_acc(
    const float in[NNB][LPAD], const float* __restrict__ W,
    int rg, int c0, float acc[4][4])
{
    #pragma unroll 2
    for (int j = 0; j < NDIM; j += 2) {
        float4 w0 = *(const float4*)&W[j * NDIM + c0];
        float4 w1 = *(const float4*)&W[(j + 1) * NDIM + c0];
        #pragma unroll
        for (int r = 0; r < 4; r++) {
            float2 a = *(const float2*)&in[rg * 4 + r][j];
            acc[r][0] += a.x * w0.x; acc[r][1] += a.x * w0.y;
            acc[r][2] += a.x * w0.z; acc[r][3] += a.x * w0.w;
            acc[r][0] += a.y * w1.x; acc[r][1] += a.y * w1.y;
            acc[r][2] += a.y * w1.z; acc[r][3] += a.y * w1.w;
        }
    }
}

__global__ __launch_bounds__(256) void attn_kernel(
    const float* __restrict__ F, const float* __restrict__ X,
    const float* __restrict__ NUV, const int* __restrict__ TOPK,
    const float* __restrict__ gW1, const float* __restrict__ gb1,
    const float* __restrict__ gW2, const float* __restrict__ gb2,
    const float* __restrict__ kW1, const float* __restrict__ kb1,
    const float* __restrict__ kW2, const float* __restrict__ kb2,
    const float* __restrict__ vW1, const float* __restrict__ vb1,
    const float* __restrict__ vW2, const float* __restrict__ vb2,
    const float* __restrict__ Q, float* __restrict__ ATT, int n)
{
    __shared__ float bufA[NNB][LPAD];
    __shared__ float bufB[NNB][LPAD];
    __shared__ float bufC[NNB][LPAD];
    __shared__ float sQ[NHEAD][NDIM];
    __shared__ float sP[NHEAD][NNB];
    __shared__ float sRL[NNB][12];
    __shared__ float sdis[NNB];
    __shared__ int   sidx[NNB];
    __shared__ float snuv[9];
    __shared__ float sx[3];

    const int pid = blockIdx.x;
    const int t = threadIdx.x;
    const int cg = t & 31, rg = t >> 5;
    const int c0 = cg * 4;

    // Q row for this point: 1024 floats, one float4 per thread
    {
        float4 q4 = *(const float4*)&Q[(size_t)pid * 1024 + t * 4];
        *(float4*)&((float*)sQ)[t * 4] = q4;
    }
    if (t < 9) snuv[t] = NUV[(size_t)pid * 9 + t];
    if (t < 3) sx[t] = X[(size_t)pid * 3 + t];
    if (t < NNB) sidx[t] = TOPK[(size_t)pid * NNB + t];
    __syncthreads();

    // geometry: RL (32 x 12) and dis
    if (t < NNB) {
        const int k = t;
        const int idx = sidx[k];
        float ox = X[(size_t)idx * 3 + 0] - sx[0];
        float oy = X[(size_t)idx * 3 + 1] - sx[1];
        float oz = X[(size_t)idx * 3 + 2] - sx[2];
        sdis[k] = __expf(-0.5f * (ox * ox + oy * oy + oz * oz));
        #pragma unroll
        for (int i = 0; i < 3; i++)
            sRL[k][i] = snuv[i * 3 + 0] * ox + snuv[i * 3 + 1] * oy + snuv[i * 3 + 2] * oz;
        #pragma unroll
        for (int r = 0; r < 3; r++) {
            float a0 = NUV[(size_t)idx * 9 + r * 3 + 0];
            float a1 = NUV[(size_t)idx * 9 + r * 3 + 1];
            float a2 = NUV[(size_t)idx * 9 + r * 3 + 2];
            #pragma unroll
            for (int i = 0; i < 3; i++)
                sRL[k][3 + r * 3 + i] =
                    snuv[i * 3 + 0] * a0 + snuv[i * 3 + 1] * a1 + snuv[i * 3 + 2] * a2;
        }
    }
    __syncthreads();

    // geo layer 1: (32x12)@(12x128) + b, elu -> bufA
    {
        float acc[4][4];
        #pragma unroll
        for (int r = 0; r < 4; r++)
            for (int c = 0; c < 4; c++) acc[r][c] = 0.f;
        #pragma unroll
        for (int j = 0; j < 12; j++) {
            float4 w = *(const float4*)&gW1[j * NDIM + c0];
            #pragma unroll
            for (int r = 0; r < 4; r++) {
                float a = sRL[rg * 4 + r][j];
                acc[r][0] += a * w.x; acc[r][1] += a * w.y;
                acc[r][2] += a * w.z; acc[r][3] += a * w.w;
            }
        }
        float4 bv = *(const float4*)&gb1[c0];
        #pragma unroll
        for (int r = 0; r < 4; r++) {
            bufA[rg * 4 + r][c0 + 0] = elu_f(acc[r][0] + bv.x);
            bufA[rg * 4 + r][c0 + 1] = elu_f(acc[r][1] + bv.y);
            bufA[rg * 4 + r][c0 + 2] = elu_f(acc[r][2] + bv.z);
            bufA[rg * 4 + r][c0 + 3] = elu_f(acc[r][3] + bv.w);
        }
    }
    __syncthreads();

    // geo layer 2 + dis*geo*features_nn -> bufB
    {
        float acc[4][4];
        #pragma unroll
        for (int r = 0; r < 4; r++)
            for (int c = 0; c < 4; c++) acc[r][c] = 0.f;
        mm32_acc(bufA, gW2, rg, c0, acc);
        float4 bv = *(const float4*)&gb2[c0];
        #pragma unroll
        for (int r = 0; r < 4; r++) {
            const int k = rg * 4 + r;
            const int idx = sidx[k];
            const float d = sdis[k];
            float4 f = *(const float4*)&F[(size_t)idx * NDIM + c0];
            bufB[k][c0 + 0] = elu_f(acc[r][0] + bv.x) * d * f.x;
            bufB[k][c0 + 1] = elu_f(acc[r][1] + bv.y) * d * f.y;
            bufB[k][c0 + 2] = elu_f(acc[r][2] + bv.z) * d * f.z;
            bufB[k][c0 + 3] = elu_f(acc[r][3] + bv.w) * d * f.w;
        }
    }
    __syncthreads();

    // K layer 1: bufB @ kW1, elu -> bufA
    {
        float acc[4][4];
        #pragma unroll
        for (int r = 0; r < 4; r++)
            for (int c = 0; c < 4; c++) acc[r][c] = 0.f;
        mm32_acc(bufB, kW1, rg, c0, acc);
        float4 bv = *(const float4*)&kb1[c0];
        #pragma unroll
        for (int r = 0; r < 4; r++) {
            bufA[rg * 4 + r][c0 + 0] = elu_f(acc[r][0] + bv.x);
            bufA[rg * 4 + r][c0 + 1] = elu_f(acc[r][1] + bv.y);
            bufA[rg * 4 + r][c0 + 2] = elu_f(acc[r][2] + bv.z);
            bufA[rg * 4 + r][c0 + 3] = elu_f(acc[r][3] + bv.w);
        }
    }
    __syncthreads();

    // K layer 2: bufA @ kW2 + kb2 -> bufC
    {
        float acc[4][4];
        #pragma unroll
        for (int r = 0; r < 4; r++)
            for (int c = 0; c < 4; c++) acc[r][c] = 0.f;
        mm32_acc(bufA, kW2, rg, c0, acc);
        float4 bv = *(const float4*)&kb2[c0];
        #pragma unroll
        for (int r = 0; r < 4; r++) {
            bufC[rg * 4 + r][c0 + 0] = acc[r][0] + bv.x;
            bufC[rg * 4 + r][c0 + 1] = acc[r][1] + bv.y;
            bufC[rg * 4 + r][c0 + 2] = acc[r][2] + bv.z;
            bufC[rg * 4 + r][c0 + 3] = acc[r][3] + bv.w;
        }
    }
    __syncthreads();

    // V layer 1: bufB @ vW1, elu -> bufA
    {
        float acc[4][4];
        #pragma unroll
        for (int r = 0; r < 4; r++)
            for (int c = 0; c < 4; c++) acc[r][c] = 0.f;
        mm32_acc(bufB, vW1, rg, c0, acc);
        float4 bv = *(const float4*)&vb1[c0];
        #pragma unroll
        for (int r = 0; r < 4; r++) {
            bufA[rg * 4 + r][c0 + 0] = elu_f(acc[r][0] + bv.x);
            bufA[rg * 4 + r][c0 + 1] = elu_f(acc[r][1] + bv.y);
            bufA[rg * 4 + r][c0 + 2] = elu_f(acc[r][2] + bv.z);
            bufA[rg * 4 + r][c0 + 3] = elu_f(acc[r][3] + bv.w);
        }
    }
    __syncthreads();

    // V layer 2: bufA @ vW2 + vb2 -> bufB (geo no longer needed)
    {
        float acc[4][4];
        #pragma unroll
        for (int r = 0; r < 4; r++)
            for (int c = 0; c < 4; c++) acc[r][c] = 0.f;
        mm32_acc(bufA, vW2, rg, c0, acc);
        float4 bv = *(const float4*)&vb2[c0];
        #pragma unroll
        for (int r = 0; r < 4; r++) {
            bufB[rg * 4 + r][c0 + 0] = acc[r][0] + bv.x;
            bufB[rg * 4 + r][c0 + 1] = acc[r][1] + bv.y;
            bufB[rg * 4 + r][c0 + 2] = acc[r][2] + bv.z;
            bufB[rg * 4 + r][c0 + 3] = acc[r][3] + bv.w;
        }
    }
    __syncthreads();

    // Mq = softmax( (Q @ K^T)/sqrt(128), mask topk==0 )  : one (h,k) per thread
    {
        const int h = t >> 5;
        const int k = t & 31;
        float m = 0.f;
        #pragma unroll 4
        for (int d = 0; d < NDIM; d += 2) {
            float2 q2 = *(const float2*)&sQ[h][d];
            float2 k2 = *(const float2*)&bufC[k][d];
            m += q2.x * k2.x + q2.y * k2.y;
        }
        m *= 0.08838834764831845f;  // 1/sqrt(128)
        if (sidx[k] == 0) m = -INFINITY;
        float mx = m;
        #pragma unroll
        for (int s = 16; s >= 1; s >>= 1) mx = fmaxf(mx, __shfl_xor(mx, s));
        float e = __expf(m - mx);
        float sum = e;
        #pragma unroll
        for (int s = 16; s >= 1; s >>= 1) sum += __shfl_xor(sum, s);
        sP[h][k] = e / sum;
    }
    __syncthreads();

    // out[h][d] = sum_k P[h][k] * V[k][d]
    {
        const int h = t >> 5;
        float o0 = 0.f, o1 = 0.f, o2 = 0.f, o3 = 0.f;
        #pragma unroll 4
        for (int k = 0; k < NNB; k++) {
            float p = sP[h][k];
            const float* vr = bufB[k];
            o0 += p * vr[c0 + 0]; o1 += p * vr[c0 + 1];
            o2 += p * vr[c0 + 2]; o3 += p * vr[c0 + 3];
        }
        *(float4*)&ATT[(size_t)pid * 1024 + h * NDIM + c0] = make_float4(o0, o1, o2, o3);
    }
}

// ---------------------------------------------------------------------------
// Kernel 3: out = LN( elu(ATT @ dW1 + db1) @ dW2 + db2 + F ) * g + b
// ---------------------------------------------------------------------------
__global__ __launch_bounds__(256) void decode_kernel(
    const float* __restrict__ ATT,
    const float* __restrict__ W1, const float* __restrict__ b1,
    const float* __restrict__ W2, const float* __restrict__ b2,
    const float* __restrict__ F,
    const float* __restrict__ lng, const float* __restrict__ lnb,
    float* __restrict__ OUT, int n)
{
    __shared__ float sIn[64][NDIM];
    __shared__ float sH[64][NDIM];
    const int t = threadIdx.x;
    const int row0 = blockIdx.x * 64;
    const int cg = t & 31, rg = t >> 5;
    const int c0 = cg * 4;

    float acc[8][4];
    #pragma unroll
    for (int r = 0; r < 8; r++)
        for (int c = 0; c < 4; c++) acc[r][c] = 0.f;

    // layer 1: 1024 -> 128 in 8 chunks of 128
    for (int kc = 0; kc < 8; kc++) {
        __syncthreads();
        for (int i = t; i < 64 * 32; i += 256) {
            int r = i >> 5;
            int c4 = (i & 31) * 4;
            int gr = row0 + r;
            float4 v = make_float4(0.f, 0.f, 0.f, 0.f);
            if (gr < n) v = *(const float4*)&ATT[(size_t)gr * 1024 + kc * 128 + c4];
            *(float4*)&sIn[r][c4] = v;
        }
        __syncthreads();
        #pragma unroll 2
        for (int j = 0; j < NDIM; j += 2) {
            float4 w0 = *(const float4*)&W1[(kc * 128 + j) * NDIM + c0];
            float4 w1 = *(const float4*)&W1[(kc * 128 + j + 1) * NDIM + c0];
            #pragma unroll
            for (int r = 0; r < 8; r++) {
                float2 a = *(const float2*)&sIn[rg * 8 + r][j];
                acc[r][0] += a.x * w0.x; acc[r][1] += a.x * w0.y;
                acc[r][2] += a.x * w0.z; acc[r][3] += a.x * w0.w;
                acc[r][0] += a.y * w1.x; acc[r][1] += a.y * w1.y;
                acc[r][2] += a.y * w1.z; acc[r][3] += a.y * w1.w;
            }
        }
    }
    __syncthreads();
    {
        float4 bv = *(const float4*)&b1[c0];
        #pragma unroll
        for (int r = 0; r < 8; r++) {
            sH[rg * 8 + r][c0 + 0] = elu_f(acc[r][0] + bv.x);
            sH[rg * 8 + r][c0 + 1] = elu_f(acc[r][1] + bv.y);
            sH[rg * 8 + r][c0 + 2] = elu_f(acc[r][2] + bv.z);
            sH[rg * 8 + r][c0 + 3] = elu_f(acc[r][3] + bv.w);
        }
    }
    __syncthreads();

    // layer 2: 128 -> 128, + residual, LayerNorm
    float a2[8][4];
    #pragma unroll
    for (int r = 0; r < 8; r++)
        for (int c = 0; c < 4; c++) a2[r][c] = 0.f;
    #pragma unroll 2
    for (int j = 0; j < NDIM; j += 2) {
        float4 w0 = *(const float4*)&W2[j * NDIM + c0];
        float4 w1 = *(const float4*)&W2[(j + 1) * NDIM + c0];
        #pragma unroll
        for (int r = 0; r < 8; r++) {
            float2 a = *(const float2*)&sH[rg * 8 + r][j];
            a2[r][0] += a.x * w0.x; a2[r][1] += a.x * w0.y;
            a2[r][2] += a.x * w0.z; a2[r][3] += a.x * w0.w;
            a2[r][0] += a.y * w1.x; a2[r][1] += a.y * w1.y;
            a2[r][2] += a.y * w1.z; a2[r][3] += a.y * w1.w;
        }
    }
    float4 bv = *(const float4*)&b2[c0];
    float4 gv = *(const float4*)&lng[c0];
    float4 bbv = *(const float4*)&lnb[c0];
    #pragma unroll
    for (int r = 0; r < 8; r++) {
        int gr = row0 + rg * 8 + r;
        float4 fres = make_float4(0.f, 0.f, 0.f, 0.f);
        if (gr < n) fres = *(const float4*)&F[(size_t)gr * NDIM + c0];
        float v0 = a2[r][0] + bv.x + fres.x;
        float v1 = a2[r][1] + bv.y + fres.y;
        float v2 = a2[r][2] + bv.z + fres.z;
        float v3 = a2[r][3] + bv.w + fres.w;
        float s = v0 + v1 + v2 + v3;
        #pragma unroll
        for (int sh = 16; sh >= 1; sh >>= 1) s += __shfl_xor(s, sh);
        float mu = s * (1.0f / 128.0f);
        float q = (v0 - mu) * (v0 - mu) + (v1 - mu) * (v1 - mu) +
                  (v2 - mu) * (v2 - mu) + (v3 - mu) * (v3 - mu);
        #pragma unroll
        for (int sh = 16; sh >= 1; sh >>= 1) q += __shfl_xor(q, sh);
        float rstd = rsqrtf(q * (1.0f / 128.0f) + 1e-5f);
        if (gr < n) {
            float4 o = make_float4((v0 - mu) * rstd * gv.x + bbv.x,
                                   (v1 - mu) * rstd * gv.y + bbv.y,
                                   (v2 - mu) * rstd * gv.z + bbv.z,
                                   (v3 - mu) * rstd * gv.w + bbv.w);
            *(float4*)&OUT[(size_t)gr * NDIM + c0] = o;
        }
    }
}

// ---------------------------------------------------------------------------
extern "C" void kernel_launch(void* const* d_in, const int* in_sizes, int n_in,
                              void* d_out, int out_size, void* d_ws, size_t ws_size,
                              hipStream_t stream)
{
    const float* F    = (const float*)d_in[0];
    const float* X    = (const float*)d_in[1];
    const float* NUV  = (const float*)d_in[2];
    const int*   TOPK = (const int*)d_in[3];
    const float* qW1  = (const float*)d_in[4];
    const float* qb1  = (const float*)d_in[5];
    const float* qW2  = (const float*)d_in[6];
    const float* qb2  = (const float*)d_in[7];
    const float* gW1  = (const float*)d_in[8];
    const float* gb1  = (const float*)d_in[9];
    const float* gW2  = (const float*)d_in[10];
    const float* gb2  = (const float*)d_in[11];
    const float* kW1  = (const float*)d_in[12];
    const float* kb1  = (const float*)d_in[13];
    const float* kW2  = (const float*)d_in[14];
    const float* kb2  = (const float*)d_in[15];
    const float* vW1  = (const float*)d_in[16];
    const float* vb1  = (const float*)d_in[17];
    const float* vW2  = (const float*)d_in[18];
    const float* vb2  = (const float*)d_in[19];
    const float* dW1  = (const float*)d_in[20];
    const float* db1  = (const float*)d_in[21];
    const float* dW2  = (const float*)d_in[22];
    const float* db2  = (const float*)d_in[23];
    const float* lng  = (const float*)d_in[24];
    const float* lnb  = (const float*)d_in[25];

    const int n = in_sizes[0] / NDIM;

    float* Qb  = (float*)d_ws;                 // n*1024 f32
    float* ATT = Qb + (size_t)n * 1024;        // n*1024 f32

    const int nb = (n + 63) / 64;
    qmlp_kernel<<<nb, 256, 0, stream>>>(F, qW1, qb1, qW2, qb2, Qb, n);
    attn_kernel<<<n, 256, 0, stream>>>(F, X, NUV, TOPK,
                                       gW1, gb1, gW2, gb2,
                                       kW1, kb1, kW2, kb2,
                                       vW1, vb1, vW2, vb2,
                                       Qb, ATT, n);
    decode_kernel<<<nb, 256, 0, stream>>>(ATT, dW1, db1, dW2, db2,
                                          F, lng, lnb, (float*)d_out, n);
}

// Round 2
// 546.806 us; speedup vs baseline: 3.7930x; 3.7930x over previous
//
#include <hip/hip_runtime.h>
#include <math.h>
#include <stdint.h>

#define ND 128
#define NNB 32
#define NH 8

typedef __attribute__((ext_vector_type(8))) short bf16x8;
typedef __attribute__((ext_vector_type(4))) float f32x4;
typedef __attribute__((ext_vector_type(8))) unsigned short u16x8;
typedef unsigned short u16;
typedef unsigned int u32;
typedef unsigned long long u64;

// ---- ws layout (bytes) ----
#define OFF_QW1T 0ULL
#define OFF_QW2T 32768ULL
#define OFF_GW2T 294912ULL
#define OFF_KW1T 327680ULL
#define OFF_KW2T 360448ULL
#define OFF_VW1T 393216ULL
#define OFF_VW2T 425984ULL
#define OFF_DW1T 458752ULL
#define OFF_DW2T 720896ULL
#define OFF_Q    753664ULL
#define QROWS    20096ULL                      // 20000 padded to 128
#define OFF_ATT  (OFF_Q + QROWS * 2048ULL)

__device__ __forceinline__ u16 rneb(float f){
    u32 u = __builtin_bit_cast(u32, f);
    u32 r = u + 0x7fffu + ((u >> 16) & 1u);
    return (u16)(r >> 16);
}
__device__ __forceinline__ float b2f(u16 h){ return __builtin_bit_cast(float, (u32)h << 16); }
__device__ __forceinline__ float elu_f(float v){ return v > 0.f ? v : (__expf(v) - 1.f); }
__device__ __forceinline__ u64 pack4(float a, float b, float c, float d){
    return (u64)rneb(a) | ((u64)rneb(b) << 16) | ((u64)rneb(c) << 32) | ((u64)rneb(d) << 48);
}

// async global->LDS, 16B per lane. LDS dest must be linear (base + lane*16).
#define GLDS16(g, l) __builtin_amdgcn_global_load_lds( \
    (const __attribute__((address_space(1))) u32*)(g), \
    (__attribute__((address_space(3))) u32*)(u32)(u64)(l), 16, 0, 0)

__device__ __forceinline__ void stage_lds(char* lds, const char* g, int bytes){
    const int t = threadIdx.x;
    for (int i = t * 16; i < bytes; i += 4096)
        GLDS16(g + i, lds + i);
}
// stage 128 rows of 256B from strided global into [128][256B] LDS tile
__device__ __forceinline__ void stage_rows(char* lds, const char* g, size_t gstride){
    const int t = threadIdx.x;
    const int seg = (t & 15) * 16, rr = t >> 4;
    #pragma unroll
    for (int i = 0; i < 8; i++){
        int row = i * 16 + rr;
        GLDS16(g + (size_t)row * gstride + seg, lds + row * 256 + seg);
    }
}

// swizzled fragment read: row-major [*][128] bf16 tile, byte ^= (row&7)<<4
__device__ __forceinline__ bf16x8 ldfrag(const u16* base, int row, int kb, int l){
    int r = row + (l & 15);
    int byte = (r << 8) + (((kb << 1) + ((l >> 4) << 4)) ^ ((r & 7) << 4));
    return *(const bf16x8*)((const char*)base + byte);
}

__device__ __forceinline__ void store_cfrag(u16* out, int m0t, int n0t, int l, f32x4 v){
    int col = n0t + (l & 15);
    int r0 = m0t + ((l >> 4) << 2);
    #pragma unroll
    for (int j = 0; j < 4; j++){
        int r = r0 + j;
        int byte = (r << 8) + (((col << 1)) ^ ((r & 7) << 4));
        *(u16*)((char*)out + byte) = rneb(v[j]);
    }
}

// 128x128x128 GEMM, 4 waves in 2x2, acc += A@B ; A,B are swizzled bf16 [128][128]
__device__ __forceinline__ void gemm_tile(const u16* A, const u16* B, f32x4 acc[4][4]){
    const int l = threadIdx.x & 63;
    const int m0 = ((threadIdx.x >> 7) & 1) * 64;
    const int n0 = ((threadIdx.x >> 6) & 1) * 64;
    #pragma unroll
    for (int kk = 0; kk < 4; kk++){
        const int kb = kk * 32;
        bf16x8 a[4], b[4];
        #pragma unroll
        for (int i = 0; i < 4; i++) a[i] = ldfrag(A, m0 + i * 16, kb, l);
        #pragma unroll
        for (int i = 0; i < 4; i++) b[i] = ldfrag(B, n0 + i * 16, kb, l);
        #pragma unroll
        for (int mt = 0; mt < 4; mt++)
            #pragma unroll
            for (int nt = 0; nt < 4; nt++)
                acc[mt][nt] = __builtin_amdgcn_mfma_f32_16x16x32_bf16(a[mt], b[nt], acc[mt][nt], 0, 0, 0);
    }
}

// ---------------------------------------------------------------------------
// prep: W (KxN f32) -> Wt (NxK bf16), pre-swizzled byte ^= (n&7)<<4 per row
// ---------------------------------------------------------------------------
struct PrepDesc {
    const float* src[9];
    u64 dstoff[9];
    int K[9], N[9];
};

__global__ __launch_bounds__(256) void prep_weights(PrepDesc d, char* ws){
    int tid = blockIdx.x * 256 + threadIdx.x;
    #pragma unroll 1
    for (int m = 0; m < 9; m++){
        int cnt = (d.K[m] * d.N[m]) >> 3;
        if (tid < cnt){
            int N = d.N[m], K = d.K[m];
            int nn = tid % N, k8 = tid / N;
            const float* s = d.src[m];
            u16x8 pk;
            #pragma unroll
            for (int i = 0; i < 8; i++)
                pk[i] = rneb(s[(size_t)(k8 * 8 + i) * N + nn]);
            u64 off = d.dstoff[m] + (u64)nn * (u64)(K * 2) + (u32)((k8 * 16) ^ ((nn & 7) << 4));
            *(u16x8*)(ws + off) = pk;
            return;
        }
        tid -= cnt;
    }
}

// ---------------------------------------------------------------------------
// qmlp: Q = elu(F@qW1+qb1)@qW2+qb2 -> bf16 swizzled Q buffer in ws
// ---------------------------------------------------------------------------
__global__ __launch_bounds__(256) void qmlp_kernel(
    const float* __restrict__ F, const float* __restrict__ qb1, const float* __restrict__ qb2,
    const char* __restrict__ ws, u16* __restrict__ Qg, int n)
{
    __shared__ u16 sIn[16384];
    __shared__ u16 sH[16384];
    __shared__ u16 sW[16384];
    const int t = threadIdx.x;
    const int row0 = blockIdx.x * 128;
    const int l = t & 63;
    const int m0 = ((t >> 7) & 1) * 64;
    const int n0 = ((t >> 6) & 1) * 64;

    stage_lds((char*)sW, ws + OFF_QW1T, 32768);
    for (int i = t; i < 4096; i += 256){
        int r = i >> 5, c = (i & 31) * 4;
        int gr = row0 + r;
        float4 v = make_float4(0.f, 0.f, 0.f, 0.f);
        if (gr < n) v = *(const float4*)&F[(size_t)gr * ND + c];
        *(u64*)((char*)sIn + (r << 8) + (((c << 1)) ^ ((r & 7) << 4))) = pack4(v.x, v.y, v.z, v.w);
    }
    __syncthreads();

    f32x4 acc[4][4];
    #pragma unroll
    for (int i = 0; i < 4; i++)
        #pragma unroll
        for (int j = 0; j < 4; j++) acc[i][j] = 0.f;
    gemm_tile(sIn, sW, acc);
    __syncthreads();
    stage_lds((char*)sW, ws + OFF_QW2T, 32768);
    #pragma unroll
    for (int mt = 0; mt < 4; mt++)
        #pragma unroll
        for (int nt = 0; nt < 4; nt++){
            int col = n0 + nt * 16 + (l & 15);
            float bv = qb1[col];
            f32x4 v;
            #pragma unroll
            for (int j = 0; j < 4; j++) v[j] = elu_f(acc[mt][nt][j] + bv);
            store_cfrag(sH, m0 + mt * 16, n0 + nt * 16, l, v);
        }
    __syncthreads();

    for (int ct = 0; ct < 8; ct++){
        f32x4 a2[4][4];
        #pragma unroll
        for (int i = 0; i < 4; i++)
            #pragma unroll
            for (int j = 0; j < 4; j++) a2[i][j] = 0.f;
        gemm_tile(sH, sW, a2);
        __syncthreads();
        if (ct < 7) stage_lds((char*)sW, ws + OFF_QW2T + (u64)(ct + 1) * 32768, 32768);
        const u32 key = ((u32)ct & 7) << 4;
        #pragma unroll
        for (int mt = 0; mt < 4; mt++)
            #pragma unroll
            for (int nt = 0; nt < 4; nt++){
                int col = n0 + nt * 16 + (l & 15);
                float bv = qb2[ct * 128 + col];
                int r0 = m0 + mt * 16 + ((l >> 4) << 2);
                #pragma unroll
                for (int j = 0; j < 4; j++){
                    int r = r0 + j;
                    *(u16*)((char*)sIn + (r << 8) + (((u32)(col << 1)) ^ key)) = rneb(a2[mt][nt][j] + bv);
                }
            }
        __syncthreads();
        {
            int row = t >> 1, half = t & 1;
            int gr = row0 + row;
            if (gr < n){
                const char* src = (const char*)sIn + (row << 8) + half * 128;
                char* dst = (char*)Qg + (size_t)gr * 2048 + ct * 256 + half * 128;
                #pragma unroll
                for (int i = 0; i < 8; i++)
                    *(uint4*)(dst + i * 16) = *(const uint4*)(src + i * 16);
            }
        }
        __syncthreads();
    }
}

// ---------------------------------------------------------------------------
// attn: fused geometry + geo/K/V MLPs (MFMA) + attention ; 4 points per block
// ---------------------------------------------------------------------------
__shared__ u16 g_dummy[1]; // (unused; keeps clang happy about shared attr ordering)

template<int ACT> // 0: linear, 1: elu, 2: linear * dis * F_nn
__device__ __forceinline__ void layer128(
    const u16* inB, u16* outB, const u16* W, const float* bias,
    const char* nextW, char* sWc,
    const float* F, const int* sidx, const float* sdis)
{
    const int l = threadIdx.x & 63;
    const int m0 = ((threadIdx.x >> 7) & 1) * 64;
    const int n0 = ((threadIdx.x >> 6) & 1) * 64;
    float fv[4][4][4];
    if (ACT == 2){
        #pragma unroll
        for (int mt = 0; mt < 4; mt++)
            #pragma unroll
            for (int nt = 0; nt < 4; nt++){
                int col = n0 + nt * 16 + (l & 15);
                int r0 = m0 + mt * 16 + ((l >> 4) << 2);
                #pragma unroll
                for (int j = 0; j < 4; j++){
                    int r = r0 + j;
                    fv[mt][nt][j] = sdis[r] * F[(size_t)sidx[r] * ND + col];
                }
            }
    }
    f32x4 acc[4][4];
    #pragma unroll
    for (int i = 0; i < 4; i++)
        #pragma unroll
        for (int j = 0; j < 4; j++) acc[i][j] = 0.f;
    gemm_tile(inB, W, acc);
    __syncthreads();
    if (nextW) stage_lds(sWc, nextW, 32768);
    #pragma unroll
    for (int mt = 0; mt < 4; mt++)
        #pragma unroll
        for (int nt = 0; nt < 4; nt++){
            int col = n0 + nt * 16 + (l & 15);
            float bv = bias[col];
            f32x4 v;
            #pragma unroll
            for (int j = 0; j < 4; j++){
                float x = acc[mt][nt][j] + bv;
                if (ACT == 1) x = elu_f(x);
                if (ACT == 2) x = x * fv[mt][nt][j];
                v[j] = x;
            }
            store_cfrag(outB, m0 + mt * 16, n0 + nt * 16, l, v);
        }
    __syncthreads();
}

__global__ __launch_bounds__(256) void attn_kernel(
    const float* __restrict__ F, const float* __restrict__ X,
    const float* __restrict__ NUV, const int* __restrict__ TOPK,
    const float* __restrict__ gW1, const float* __restrict__ gb1,
    const float* __restrict__ gb2,
    const float* __restrict__ kb1, const float* __restrict__ kb2,
    const float* __restrict__ vb1, const float* __restrict__ vb2,
    const char* __restrict__ ws, u16* __restrict__ ATT)
{
    __shared__ u16 buf0[16384];
    __shared__ u16 buf1[16384];
    __shared__ u16 sW[16384];
    __shared__ u16 sQ[8192];          // 4 x [16][128]
    __shared__ float sRL[128][12];
    __shared__ float sP[4][32][9];
    __shared__ float sdis[128];
    __shared__ int   sidx[128];

    const int t = threadIdx.x;
    const int pid0 = blockIdx.x * 4;

    // stage first weight + Q tiles (async)
    stage_lds((char*)sW, ws + OFF_GW2T, 32768);
    {
        int w = t >> 6, lane = t & 63;
        const char* gq = ws + OFF_Q + (size_t)(pid0 + w) * 2048;
        char* lq = (char*)sQ + w * 4096;
        GLDS16(gq + lane * 16, lq + lane * 16);
        GLDS16(gq + 1024 + lane * 16, lq + 1024 + lane * 16);
    }

    // geometry: RL(12), dis, idx for 128 neighbor rows
    if (t < 128){
        int p = t >> 5, k = t & 31;
        int pid = pid0 + p;
        int idx = TOPK[(size_t)pid * NNB + k];
        sidx[t] = idx;
        float x0 = X[(size_t)pid * 3 + 0], x1 = X[(size_t)pid * 3 + 1], x2 = X[(size_t)pid * 3 + 2];
        float ox = X[(size_t)idx * 3 + 0] - x0;
        float oy = X[(size_t)idx * 3 + 1] - x1;
        float oz = X[(size_t)idx * 3 + 2] - x2;
        sdis[t] = __expf(-0.5f * (ox * ox + oy * oy + oz * oz));
        float nv[9];
        #pragma unroll
        for (int i = 0; i < 9; i++) nv[i] = NUV[(size_t)pid * 9 + i];
        #pragma unroll
        for (int i = 0; i < 3; i++)
            sRL[t][i] = nv[i * 3 + 0] * ox + nv[i * 3 + 1] * oy + nv[i * 3 + 2] * oz;
        #pragma unroll
        for (int r = 0; r < 3; r++){
            float a0 = NUV[(size_t)idx * 9 + r * 3 + 0];
            float a1 = NUV[(size_t)idx * 9 + r * 3 + 1];
            float a2 = NUV[(size_t)idx * 9 + r * 3 + 2];
            #pragma unroll
            for (int i = 0; i < 3; i++)
                sRL[t][3 + r * 3 + i] = nv[i * 3 + 0] * a0 + nv[i * 3 + 1] * a1 + nv[i * 3 + 2] * a2;
        }
    }
    __syncthreads();

    // geo L1 (12->128, elu) vector -> buf0 (swizzled bf16)
    {
        const int cg = t & 31, rg = t >> 5;
        const int c0 = cg * 4;
        for (int p = 0; p < 4; p++){
            float acc[4][4];
            #pragma unroll
            for (int r = 0; r < 4; r++)
                #pragma unroll
                for (int c = 0; c < 4; c++) acc[r][c] = 0.f;
            #pragma unroll
            for (int j = 0; j < 12; j++){
                float4 w = *(const float4*)&gW1[j * ND + c0];
                #pragma unroll
                for (int r = 0; r < 4; r++){
                    float a = sRL[p * 32 + rg * 4 + r][j];
                    acc[r][0] += a * w.x; acc[r][1] += a * w.y;
                    acc[r][2] += a * w.z; acc[r][3] += a * w.w;
                }
            }
            float4 bv = *(const float4*)&gb1[c0];
            #pragma unroll
            for (int r = 0; r < 4; r++){
                int row = p * 32 + rg * 4 + r;
                u64 pk = pack4(elu_f(acc[r][0] + bv.x), elu_f(acc[r][1] + bv.y),
                               elu_f(acc[r][2] + bv.z), elu_f(acc[r][3] + bv.w));
                *(u64*)((char*)buf0 + (row << 8) + (((c0 << 1)) ^ ((row & 7) << 4))) = pk;
            }
        }
    }
    __syncthreads();   // buf0, sW(gW2t), sQ ready

    // 5 MFMA layers
    layer128<2>(buf0, buf0, sW, gb2, ws + OFF_KW1T, (char*)sW, F, sidx, sdis); // geo L2 * dis * F
    layer128<1>(buf0, buf1, sW, kb1, ws + OFF_KW2T, (char*)sW, F, sidx, sdis); // K1
    layer128<0>(buf1, buf1, sW, kb2, ws + OFF_VW1T, (char*)sW, F, sidx, sdis); // K2 -> K in buf1
    layer128<1>(buf0, buf0, sW, vb1, ws + OFF_VW2T, (char*)sW, F, sidx, sdis); // V1
    layer128<0>(buf0, buf0, sW, vb2, nullptr,       (char*)sW, F, sidx, sdis); // V2 -> V in buf0

    // S^T = K @ Q^T (per wave = per point), then softmax over k
    {
        const int l = t & 63, w = t >> 6;
        f32x4 s0, s1;
        s0 = 0.f; s1 = 0.f;
        const u16* Qt = sQ + w * 2048;
        #pragma unroll
        for (int kk = 0; kk < 4; kk++){
            int kb = kk * 32;
            bf16x8 a0 = ldfrag(buf1, w * 32, kb, l);
            bf16x8 a1 = ldfrag(buf1, w * 32 + 16, kb, l);
            bf16x8 bq = ldfrag(Qt, 0, kb, l);
            s0 = __builtin_amdgcn_mfma_f32_16x16x32_bf16(a0, bq, s0, 0, 0, 0);
            s1 = __builtin_amdgcn_mfma_f32_16x16x32_bf16(a1, bq, s1, 0, 0, 0);
        }
        const float RS = 0.08838834764831845f;
        float sv[8];
        #pragma unroll
        for (int mt = 0; mt < 2; mt++)
            #pragma unroll
            for (int j = 0; j < 4; j++){
                int kidx = mt * 16 + ((l >> 4) << 2) + j;
                float x = (mt ? s1[j] : s0[j]) * RS;
                if (sidx[w * 32 + kidx] == 0) x = -INFINITY;
                sv[mt * 4 + j] = x;
            }
        float mx = sv[0];
        #pragma unroll
        for (int i = 1; i < 8; i++) mx = fmaxf(mx, sv[i]);
        mx = fmaxf(mx, __shfl_xor(mx, 16));
        mx = fmaxf(mx, __shfl_xor(mx, 32));
        float e[8], sum = 0.f;
        #pragma unroll
        for (int i = 0; i < 8; i++){ e[i] = __expf(sv[i] - mx); sum += e[i]; }
        sum += __shfl_xor(sum, 16);
        sum += __shfl_xor(sum, 32);
        float inv = 1.f / sum;
        int h = l & 15;
        if (h < 8){
            #pragma unroll
            for (int i = 0; i < 8; i++){
                int kidx = (i >> 2) * 16 + ((l >> 4) << 2) + (i & 3);
                sP[w][kidx][h] = e[i] * inv;
            }
        }
    }
    __syncthreads();

    // PV (vector) -> ATT global (bf16, swizzled by point&7)
    {
        const int p = t >> 6, th = t & 63;
        const int h = th >> 3, d0 = (th & 7) * 16;
        float o[16];
        #pragma unroll
        for (int i = 0; i < 16; i++) o[i] = 0.f;
        #pragma unroll 4
        for (int k = 0; k < 32; k++){
            float pk = sP[p][k][h];
            int r = p * 32 + k;
            int ba = (r << 8) + (((d0 << 1)) ^ ((r & 7) << 4));
            int bb = (r << 8) + ((((d0 << 1) + 16)) ^ ((r & 7) << 4));
            bf16x8 v0 = *(const bf16x8*)((const char*)buf0 + ba);
            bf16x8 v1 = *(const bf16x8*)((const char*)buf0 + bb);
            #pragma unroll
            for (int i = 0; i < 8; i++){
                o[i]     += pk * b2f((u16)v0[i]);
                o[8 + i] += pk * b2f((u16)v1[i]);
            }
        }
        int pid = pid0 + p;
        u32 key = ((u32)pid & 7) << 4;
        int cbase = (h * ND + d0) * 2;
        u16x8 w0, w1;
        #pragma unroll
        for (int i = 0; i < 8; i++){ w0[i] = rneb(o[i]); w1[i] = rneb(o[8 + i]); }
        char* dst = (char*)ATT + (size_t)pid * 2048;
        *(u16x8*)(dst + ((u32)cbase ^ key)) = w0;
        *(u16x8*)(dst + (((u32)cbase + 16) ^ key)) = w1;
    }
}

// ---------------------------------------------------------------------------
// decode: out = LN( elu(ATT@dW1+db1)@dW2+db2 + F ) * g + b
// ---------------------------------------------------------------------------
__global__ __launch_bounds__(256) void decode_kernel(
    const u16* __restrict__ ATT,
    const float* __restrict__ db1, const float* __restrict__ db2,
    const float* __restrict__ F,
    const float* __restrict__ lng, const float* __restrict__ lnb,
    const char* __restrict__ ws, float* __restrict__ OUT, int n)
{
    __shared__ __align__(16) char SM[100352];
    u16* sA  = (u16*)SM;
    u16* sH  = (u16*)(SM + 32768);
    u16* sWk = (u16*)(SM + 67584);
    float* sO = (float*)SM;          // [128][132] f32, overlaps sA/sH/sWk after L2

    const int t = threadIdx.x;
    const int row0 = blockIdx.x * 128;
    const int l = t & 63;
    const int m0 = ((t >> 7) & 1) * 64;
    const int n0 = ((t >> 6) & 1) * 64;

    // L1: 1024 -> 128 over 8 K-chunks
    f32x4 acc[4][4];
    #pragma unroll
    for (int i = 0; i < 4; i++)
        #pragma unroll
        for (int j = 0; j < 4; j++) acc[i][j] = 0.f;
    for (int kc = 0; kc < 8; kc++){
        stage_rows((char*)sA, (const char*)ATT + (size_t)row0 * 2048 + kc * 256, 2048);
        stage_rows((char*)sWk, ws + OFF_DW1T + kc * 256, 2048);
        __syncthreads();
        gemm_tile(sA, sWk, acc);
        __syncthreads();
    }
    stage_lds((char*)sWk, ws + OFF_DW2T, 32768);
    #pragma unroll
    for (int mt = 0; mt < 4; mt++)
        #pragma unroll
        for (int nt = 0; nt < 4; nt++){
            int col = n0 + nt * 16 + (l & 15);
            float bv = db1[col];
            f32x4 v;
            #pragma unroll
            for (int j = 0; j < 4; j++) v[j] = elu_f(acc[mt][nt][j] + bv);
            store_cfrag(sH, m0 + mt * 16, n0 + nt * 16, l, v);
        }
    __syncthreads();

    // L2
    f32x4 a2[4][4];
    #pragma unroll
    for (int i = 0; i < 4; i++)
        #pragma unroll
        for (int j = 0; j < 4; j++) a2[i][j] = 0.f;
    gemm_tile(sH, sWk, a2);
    __syncthreads();   // sH/sWk dead; sO may now alias

    #pragma unroll
    for (int mt = 0; mt < 4; mt++)
        #pragma unroll
        for (int nt = 0; nt < 4; nt++){
            int col = n0 + nt * 16 + (l & 15);
            float bv = db2[col];
            int r0 = m0 + mt * 16 + ((l >> 4) << 2);
            #pragma unroll
            for (int j = 0; j < 4; j++){
                int r = r0 + j;
                int gr = row0 + r;
                float x = a2[mt][nt][j] + bv;
                if (gr < n) x += F[(size_t)gr * ND + col];
                sO[r * 132 + col] = x;
            }
        }
    __syncthreads();

    // LayerNorm: 2 threads per row (64 cols each), combine via shfl_xor(1)
    {
        int r = t >> 1, half = t & 1;
        const float* rowp = sO + r * 132 + half * 64;
        float s = 0.f;
        #pragma unroll
        for (int i = 0; i < 16; i++){
            float4 v = ((const float4*)rowp)[i];
            s += v.x + v.y + v.z + v.w;
        }
        s += __shfl_xor(s, 1);
        float mu = s * (1.f / 128.f);
        float q = 0.f;
        #pragma unroll
        for (int i = 0; i < 16; i++){
            float4 v = ((const float4*)rowp)[i];
            q += (v.x - mu) * (v.x - mu) + (v.y - mu) * (v.y - mu)
               + (v.z - mu) * (v.z - mu) + (v.w - mu) * (v.w - mu);
        }
        q += __shfl_xor(q, 1);
        float rstd = rsqrtf(q * (1.f / 128.f) + 1e-5f);
        int gr = row0 + r;
        if (gr < n){
            #pragma unroll
            for (int i = 0; i < 16; i++){
                float4 v = ((const float4*)rowp)[i];
                int c = half * 64 + i * 4;
                float4 g4 = *(const float4*)&lng[c];
                float4 b4 = *(const float4*)&lnb[c];
                float4 ov = make_float4((v.x - mu) * rstd * g4.x + b4.x,
                                        (v.y - mu) * rstd * g4.y + b4.y,
                                        (v.z - mu) * rstd * g4.z + b4.z,
                                        (v.w - mu) * rstd * g4.w + b4.w);
                *(float4*)&OUT[(size_t)gr * ND + c] = ov;
            }
        }
    }
}

// ---------------------------------------------------------------------------
extern "C" void kernel_launch(void* const* d_in, const int* in_sizes, int n_in,
                              void* d_out, int out_size, void* d_ws, size_t ws_size,
                              hipStream_t stream)
{
    const float* F    = (const float*)d_in[0];
    const float* X    = (const float*)d_in[1];
    const float* NUV  = (const float*)d_in[2];
    const int*   TOPK = (const int*)d_in[3];
    const float* qW1  = (const float*)d_in[4];
    const float* qb1  = (const float*)d_in[5];
    const float* qW2  = (const float*)d_in[6];
    const float* qb2  = (const float*)d_in[7];
    const float* gW1  = (const float*)d_in[8];
    const float* gb1  = (const float*)d_in[9];
    const float* gW2  = (const float*)d_in[10];
    const float* gb2  = (const float*)d_in[11];
    const float* kW1  = (const float*)d_in[12];
    const float* kb1  = (const float*)d_in[13];
    const float* kW2  = (const float*)d_in[14];
    const float* kb2  = (const float*)d_in[15];
    const float* vW1  = (const float*)d_in[16];
    const float* vb1  = (const float*)d_in[17];
    const float* vW2  = (const float*)d_in[18];
    const float* vb2  = (const float*)d_in[19];
    const float* dW1  = (const float*)d_in[20];
    const float* db1  = (const float*)d_in[21];
    const float* dW2  = (const float*)d_in[22];
    const float* db2  = (const float*)d_in[23];
    const float* lng  = (const float*)d_in[24];
    const float* lnb  = (const float*)d_in[25];

    const int n = in_sizes[0] / ND;
    char* wsb = (char*)d_ws;

    PrepDesc pd;
    const float* srcs[9] = {qW1, qW2, gW2, kW1, kW2, vW1, vW2, dW1, dW2};
    u64 offs[9] = {OFF_QW1T, OFF_QW2T, OFF_GW2T, OFF_KW1T, OFF_KW2T, OFF_VW1T, OFF_VW2T, OFF_DW1T, OFF_DW2T};
    int Ks[9] = {128, 128, 128, 128, 128, 128, 128, 1024, 128};
    int Ns[9] = {128, 1024, 128, 128, 128, 128, 128, 128, 128};
    for (int i = 0; i < 9; i++){ pd.src[i] = srcs[i]; pd.dstoff[i] = offs[i]; pd.K[i] = Ks[i]; pd.N[i] = Ns[i]; }

    prep_weights<<<184, 256, 0, stream>>>(pd, wsb);

    u16* Qg  = (u16*)(wsb + OFF_Q);
    u16* ATT = (u16*)(wsb + OFF_ATT);
    const int nb = (n + 127) / 128;

    qmlp_kernel<<<nb, 256, 0, stream>>>(F, qb1, qb2, wsb, Qg, n);
    attn_kernel<<<n / 4, 256, 0, stream>>>(F, X, NUV, TOPK, gW1, gb1, gb2,
                                           kb1, kb2, vb1, vb2, wsb, ATT);
    decode_kernel<<<nb, 256, 0, stream>>>(ATT, db1, db2, F, lng, lnb, wsb, (float*)d_out, n);
}

// Round 3
// 410.547 us; speedup vs baseline: 5.0519x; 1.3319x over previous
//
#include <hip/hip_runtime.h>
#include <math.h>
#include <stdint.h>

#define ND 128
#define NNB 32
#define NH 8

typedef __attribute__((ext_vector_type(8))) short bf16x8;
typedef __attribute__((ext_vector_type(4))) float f32x4;
typedef __attribute__((ext_vector_type(8))) unsigned short u16x8;
typedef unsigned short u16;
typedef unsigned int u32;
typedef unsigned long long u64;

// ---- ws layout (bytes); all weights transposed Wt[N][K] bf16, LINEAR ----
#define OFF_QW1T 0ULL
#define OFF_QW2T 32768ULL
#define OFF_GW1T 294912ULL     // [128][32] (K padded 12->32 with zeros)
#define OFF_GW2T 303104ULL
#define OFF_KW1T 335872ULL
#define OFF_KW2T 368640ULL
#define OFF_VW1T 401408ULL
#define OFF_VW2T 434176ULL
#define OFF_DW1T 466944ULL     // [128][1024]
#define OFF_DW2T 729088ULL
#define OFF_Q    761856ULL     // [20096][1024] bf16, linear
#define OFF_ATT  (OFF_Q + 20096ULL * 2048ULL)  // [20096][1024] bf16, chunk-swizzled by (row&7)

__device__ __forceinline__ u16 rneb(float f){
    u32 u = __builtin_bit_cast(u32, f);
    u32 r = u + 0x7fffu + ((u >> 16) & 1u);
    return (u16)(r >> 16);
}
__device__ __forceinline__ float elu_f(float v){ return v > 0.f ? v : (__expf(v) - 1.f); }
__device__ __forceinline__ u64 pack4(float a, float b, float c, float d){
    return (u64)rneb(a) | ((u64)rneb(b) << 16) | ((u64)rneb(c) << 32) | ((u64)rneb(d) << 48);
}

// async global->LDS, 16B per lane (linear dest = base + t*16)
#define GLDS16(g, l) __builtin_amdgcn_global_load_lds( \
    (const __attribute__((address_space(1))) u32*)(g), \
    (__attribute__((address_space(3))) u32*)(u32)(u64)(l), 16, 0, 0)

// stage 128 rows of 256B from strided global into [128][256B] LDS tile
__device__ __forceinline__ void stage_rows(char* lds, const char* g, size_t gstride){
    const int t = threadIdx.x;
    const int seg = (t & 15) * 16, rr = t >> 4;
    #pragma unroll
    for (int i = 0; i < 8; i++){
        int row = i * 16 + rr;
        GLDS16(g + (size_t)row * gstride + seg, lds + row * 256 + seg);
    }
}

// swizzled fragment read from LDS: row-major [*][128] bf16, byte ^= (row&7)<<4
__device__ __forceinline__ bf16x8 ldfrag(const u16* base, int row, int kb, int l){
    int r = row + (l & 15);
    int byte = (r << 8) + (((kb << 1) + ((l >> 4) << 4)) ^ ((r & 7) << 4));
    return *(const bf16x8*)((const char*)base + byte);
}
// B-fragment directly from global Wt[N][K] (linear, row stride kstride bytes)
__device__ __forceinline__ bf16x8 ldfragG(const char* __restrict__ Wt, int n, int kstride, int kb, int l){
    return *(const bf16x8*)(Wt + (size_t)(n + (l & 15)) * (size_t)kstride
                               + (size_t)((kb << 1) + ((l >> 4) << 4)));
}
// RL fragment: [128][32] bf16 rows of 64B, byte ^= (row&3)<<4
__device__ __forceinline__ bf16x8 ldfragRL(const u16* base, int row, int l){
    int r = row + (l & 15);
    int byte = (r << 6) + ((((l >> 4) << 4)) ^ ((r & 3) << 4));
    return *(const bf16x8*)((const char*)base + byte);
}

__device__ __forceinline__ void store_cfrag(u16* out, int m0t, int n0t, int l, f32x4 v){
    int col = n0t + (l & 15);
    int r0 = m0t + ((l >> 4) << 2);
    #pragma unroll
    for (int j = 0; j < 4; j++){
        int r = r0 + j;
        int byte = (r << 8) + (((col << 1)) ^ ((r & 7) << 4));
        *(u16*)((char*)out + byte) = rneb(v[j]);
    }
}
// transposed store: value (r,c) -> out[c][r]; 4 consecutive r pack to one u64
__device__ __forceinline__ void store_cfragT(u16* out, int m0t, int n0t, int l, f32x4 v){
    int c = n0t + (l & 15);
    int r0 = m0t + ((l >> 4) << 2);
    *(u64*)((char*)out + (c << 8) + (((r0 << 1)) ^ ((c & 7) << 4))) = pack4(v[0], v[1], v[2], v[3]);
}

// 128x128 tile GEMM, A from LDS (swizzled), B from global Wt; acc += A@B
__device__ __forceinline__ void gemm_tileG(const u16* A, const char* __restrict__ Wt,
                                           int kstride, int kbase, f32x4 acc[4][4]){
    const int t = threadIdx.x, l = t & 63;
    const int m0 = ((t >> 7) & 1) * 64;
    const int n0 = ((t >> 6) & 1) * 64;
    bf16x8 b[4][4];
    #pragma unroll
    for (int kk = 0; kk < 4; kk++)
        #pragma unroll
        for (int i = 0; i < 4; i++)
            b[kk][i] = ldfragG(Wt, n0 + i * 16, kstride, kbase + kk * 32, l);
    #pragma unroll
    for (int kk = 0; kk < 4; kk++){
        bf16x8 a[4];
        #pragma unroll
        for (int i = 0; i < 4; i++) a[i] = ldfrag(A, m0 + i * 16, kk * 32, l);
        #pragma unroll
        for (int mt = 0; mt < 4; mt++)
            #pragma unroll
            for (int nt = 0; nt < 4; nt++)
                acc[mt][nt] = __builtin_amdgcn_mfma_f32_16x16x32_bf16(a[mt], b[kk][nt], acc[mt][nt], 0, 0, 0);
    }
}

// ---------------------------------------------------------------------------
// prep: W (Ksrc x N f32) -> Wt (N x Kdst bf16, zero-padded), linear
// ---------------------------------------------------------------------------
struct PrepDesc {
    const float* src[10];
    u64 dstoff[10];
    int N[10], Ksrc[10], Kdst[10];
};

__global__ __launch_bounds__(256) void prep_weights(PrepDesc d, char* ws){
    int tid = blockIdx.x * 256 + threadIdx.x;
    #pragma unroll 1
    for (int m = 0; m < 10; m++){
        int cnt = (d.Kdst[m] * d.N[m]) >> 3;
        if (tid < cnt){
            int N = d.N[m];
            int nn = tid % N, k8 = tid / N;
            const float* s = d.src[m];
            u16x8 pk;
            #pragma unroll
            for (int i = 0; i < 8; i++){
                int k = k8 * 8 + i;
                pk[i] = (k < d.Ksrc[m]) ? rneb(s[(size_t)k * N + nn]) : (u16)0;
            }
            *(u16x8*)(ws + d.dstoff[m] + (u64)nn * (u64)(d.Kdst[m] * 2) + (u64)(k8 * 16)) = pk;
            return;
        }
        tid -= cnt;
    }
}

// ---------------------------------------------------------------------------
// qmlp: Q = elu(F@qW1+qb1)@qW2+qb2 -> bf16 LINEAR Q buffer in ws
// ---------------------------------------------------------------------------
__global__ __launch_bounds__(256, 2) void qmlp_kernel(
    const float* __restrict__ F, const float* __restrict__ qb1, const float* __restrict__ qb2,
    const char* __restrict__ ws, u16* __restrict__ Qg, int n)
{
    __shared__ __align__(16) u16 sIn[16384];
    __shared__ __align__(16) u16 sH[16384];
    const int t = threadIdx.x;
    const int row0 = blockIdx.x * 128;
    const int l = t & 63;
    const int m0 = ((t >> 7) & 1) * 64;
    const int n0 = ((t >> 6) & 1) * 64;

    // stage F (f32 -> bf16, swizzled) into sIn
    for (int i = t; i < 4096; i += 256){
        int r = i >> 5, c = (i & 31) * 4;
        int gr = row0 + r;
        float4 v = make_float4(0.f, 0.f, 0.f, 0.f);
        if (gr < n) v = *(const float4*)&F[(size_t)gr * ND + c];
        *(u64*)((char*)sIn + (r << 8) + (((c << 1)) ^ ((r & 7) << 4))) = pack4(v.x, v.y, v.z, v.w);
    }
    __syncthreads();

    // L1: 128->128, elu
    f32x4 acc[4][4];
    #pragma unroll
    for (int i = 0; i < 4; i++)
        #pragma unroll
        for (int j = 0; j < 4; j++) acc[i][j] = 0.f;
    gemm_tileG(sIn, ws + OFF_QW1T, 256, 0, acc);
    #pragma unroll
    for (int mt = 0; mt < 4; mt++)
        #pragma unroll
        for (int nt = 0; nt < 4; nt++){
            int col = n0 + nt * 16 + (l & 15);
            float bv = qb1[col];
            f32x4 v;
            #pragma unroll
            for (int j = 0; j < 4; j++) v[j] = elu_f(acc[mt][nt][j] + bv);
            store_cfrag(sH, m0 + mt * 16, n0 + nt * 16, l, v);
        }
    __syncthreads();

    // L2: 128->1024 in 8 column chunks
    for (int ct = 0; ct < 8; ct++){
        f32x4 a2[4][4];
        #pragma unroll
        for (int i = 0; i < 4; i++)
            #pragma unroll
            for (int j = 0; j < 4; j++) a2[i][j] = 0.f;
        gemm_tileG(sH, ws + OFF_QW2T + (u64)ct * 32768ULL, 256, 0, a2);
        // write to sIn UNSWIZZLED (linear), then copy out
        #pragma unroll
        for (int mt = 0; mt < 4; mt++)
            #pragma unroll
            for (int nt = 0; nt < 4; nt++){
                int col = n0 + nt * 16 + (l & 15);
                float bv = qb2[ct * 128 + col];
                int r0 = m0 + mt * 16 + ((l >> 4) << 2);
                #pragma unroll
                for (int j = 0; j < 4; j++)
                    *(u16*)((char*)sIn + ((r0 + j) << 8) + (col << 1)) = rneb(a2[mt][nt][j] + bv);
            }
        __syncthreads();
        {
            int row = t >> 1, half = t & 1;
            int gr = row0 + row;
            if (gr < n){
                const char* src = (const char*)sIn + (row << 8) + half * 128;
                char* dst = (char*)Qg + (size_t)gr * 2048 + ct * 256 + half * 128;
                #pragma unroll
                for (int i = 0; i < 8; i++)
                    *(uint4*)(dst + i * 16) = *(const uint4*)(src + i * 16);
            }
        }
        __syncthreads();
    }
}

// ---------------------------------------------------------------------------
// attn: fused geometry + geo/K/V MLPs (MFMA) + attention ; 4 points per block
// ---------------------------------------------------------------------------
template<int ACT> // 0: linear, 1: elu, 2: linear*dis*F_nn, 3: linear + transposed store
__device__ __forceinline__ void layerG(
    const u16* inB, u16* outB, const char* __restrict__ Wt,
    const float* __restrict__ bias, const float* __restrict__ F,
    const int* sidx, const float* sdis)
{
    const int t = threadIdx.x, l = t & 63;
    const int m0 = ((t >> 7) & 1) * 64;
    const int n0 = ((t >> 6) & 1) * 64;
    f32x4 acc[4][4];
    #pragma unroll
    for (int i = 0; i < 4; i++)
        #pragma unroll
        for (int j = 0; j < 4; j++) acc[i][j] = 0.f;
    gemm_tileG(inB, Wt, 256, 0, acc);
    float fv[4][4][4];
    if (ACT == 2){
        #pragma unroll
        for (int mt = 0; mt < 4; mt++)
            #pragma unroll
            for (int nt = 0; nt < 4; nt++){
                int col = n0 + nt * 16 + (l & 15);
                int r0 = m0 + mt * 16 + ((l >> 4) << 2);
                #pragma unroll
                for (int j = 0; j < 4; j++){
                    int r = r0 + j;
                    fv[mt][nt][j] = sdis[r] * F[(size_t)sidx[r] * ND + col];
                }
            }
    }
    __syncthreads();   // all reads of inB complete (allows in-place outB)
    #pragma unroll
    for (int mt = 0; mt < 4; mt++)
        #pragma unroll
        for (int nt = 0; nt < 4; nt++){
            int col = n0 + nt * 16 + (l & 15);
            float bv = bias[col];
            f32x4 v;
            #pragma unroll
            for (int j = 0; j < 4; j++){
                float x = acc[mt][nt][j] + bv;
                if (ACT == 1) x = elu_f(x);
                if (ACT == 2) x = x * fv[mt][nt][j];
                v[j] = x;
            }
            if (ACT == 3) store_cfragT(outB, m0 + mt * 16, n0 + nt * 16, l, v);
            else          store_cfrag (outB, m0 + mt * 16, n0 + nt * 16, l, v);
        }
    __syncthreads();
}

__global__ __launch_bounds__(256, 2) void attn_kernel(
    const float* __restrict__ F, const float* __restrict__ X,
    const float* __restrict__ NUV, const int* __restrict__ TOPK,
    const float* __restrict__ gb1, const float* __restrict__ gb2,
    const float* __restrict__ kb1, const float* __restrict__ kb2,
    const float* __restrict__ vb1, const float* __restrict__ vb2,
    const char* __restrict__ ws, const u16* __restrict__ Qg, u16* __restrict__ ATT)
{
    __shared__ __align__(16) u16 buf0[16384];
    __shared__ __align__(16) u16 buf1[16384];
    __shared__ __align__(16) u16 sP16[2560];   // 4 pts x 16 rows x 80B (stride 80)
    __shared__ float sdis[128];
    __shared__ int   sidx[128];

    const int t = threadIdx.x;
    const int pid0 = blockIdx.x * 4;

    // geometry: RL -> buf1 as [128][32] bf16 (swizzled, k 12..31 zero), dis, idx
    if (t < 128){
        int p = t >> 5, k = t & 31;
        int pid = pid0 + p;
        int idx = TOPK[(size_t)pid * NNB + k];
        sidx[t] = idx;
        float x0 = X[(size_t)pid * 3 + 0], x1 = X[(size_t)pid * 3 + 1], x2 = X[(size_t)pid * 3 + 2];
        float ox = X[(size_t)idx * 3 + 0] - x0;
        float oy = X[(size_t)idx * 3 + 1] - x1;
        float oz = X[(size_t)idx * 3 + 2] - x2;
        sdis[t] = __expf(-0.5f * (ox * ox + oy * oy + oz * oz));
        float nv[9];
        #pragma unroll
        for (int i = 0; i < 9; i++) nv[i] = NUV[(size_t)pid * 9 + i];
        float f[12];
        #pragma unroll
        for (int i = 0; i < 3; i++)
            f[i] = nv[i * 3 + 0] * ox + nv[i * 3 + 1] * oy + nv[i * 3 + 2] * oz;
        #pragma unroll
        for (int r = 0; r < 3; r++){
            float a0 = NUV[(size_t)idx * 9 + r * 3 + 0];
            float a1 = NUV[(size_t)idx * 9 + r * 3 + 1];
            float a2 = NUV[(size_t)idx * 9 + r * 3 + 2];
            #pragma unroll
            for (int i = 0; i < 3; i++)
                f[3 + r * 3 + i] = nv[i * 3 + 0] * a0 + nv[i * 3 + 1] * a1 + nv[i * 3 + 2] * a2;
        }
        char* rb = (char*)buf1 + (t << 6);
        u32 key = (u32)(t & 3) << 4;
        *(u64*)(rb + (0u ^ key))  = pack4(f[0], f[1], f[2], f[3]);
        *(u64*)(rb + (8u ^ key))  = pack4(f[4], f[5], f[6], f[7]);
        *(u64*)(rb + (16u ^ key)) = pack4(f[8], f[9], f[10], f[11]);
        *(u64*)(rb + (24u ^ key)) = 0ULL;
        *(u64*)(rb + (32u ^ key)) = 0ULL;
        *(u64*)(rb + (40u ^ key)) = 0ULL;
        *(u64*)(rb + (48u ^ key)) = 0ULL;
        *(u64*)(rb + (56u ^ key)) = 0ULL;
    }
    __syncthreads();

    // geo L1 (MFMA, K=32): buf1(RL) @ gW1t -> buf0, elu
    {
        const int l = t & 63;
        const int m0 = ((t >> 7) & 1) * 64;
        const int n0 = ((t >> 6) & 1) * 64;
        bf16x8 bg[4], ag[4];
        #pragma unroll
        for (int i = 0; i < 4; i++) bg[i] = ldfragG(ws + OFF_GW1T, n0 + i * 16, 64, 0, l);
        #pragma unroll
        for (int i = 0; i < 4; i++) ag[i] = ldfragRL(buf1, m0 + i * 16, l);
        f32x4 acc[4][4];
        #pragma unroll
        for (int i = 0; i < 4; i++)
            #pragma unroll
            for (int j = 0; j < 4; j++) acc[i][j] = 0.f;
        #pragma unroll
        for (int mt = 0; mt < 4; mt++)
            #pragma unroll
            for (int nt = 0; nt < 4; nt++)
                acc[mt][nt] = __builtin_amdgcn_mfma_f32_16x16x32_bf16(ag[mt], bg[nt], acc[mt][nt], 0, 0, 0);
        #pragma unroll
        for (int mt = 0; mt < 4; mt++)
            #pragma unroll
            for (int nt = 0; nt < 4; nt++){
                int col = n0 + nt * 16 + (l & 15);
                float bv = gb1[col];
                f32x4 v;
                #pragma unroll
                for (int j = 0; j < 4; j++) v[j] = elu_f(acc[mt][nt][j] + bv);
                store_cfrag(buf0, m0 + mt * 16, n0 + nt * 16, l, v);
            }
    }
    __syncthreads();

    // MFMA layers (B-frags from global)
    layerG<2>(buf0, buf0, ws + OFF_GW2T, gb2, F, sidx, sdis); // geo L2 * dis * F_nn
    layerG<1>(buf0, buf1, ws + OFF_KW1T, kb1, F, sidx, sdis); // K1
    layerG<0>(buf1, buf1, ws + OFF_KW2T, kb2, F, sidx, sdis); // K2 -> K in buf1
    layerG<1>(buf0, buf0, ws + OFF_VW1T, vb1, F, sidx, sdis); // V1
    layerG<3>(buf0, buf0, ws + OFF_VW2T, vb2, F, sidx, sdis); // V2 -> V^T in buf0

    // S^T = K @ Q^T per wave (= per point); softmax over k; P -> sP16 (bf16)
    {
        const int l = t & 63, w = t >> 6, hi = l >> 4;
        f32x4 s0, s1;
        s0 = 0.f; s1 = 0.f;
        const char* qb = (const char*)Qg + (size_t)(pid0 + w) * 2048
                       + (size_t)(l & 7) * 256 + (size_t)(hi << 4);
        #pragma unroll
        for (int kk = 0; kk < 4; kk++){
            bf16x8 bq = *(const bf16x8*)(qb + kk * 64);
            bf16x8 a0 = ldfrag(buf1, w * 32,      kk * 32, l);
            bf16x8 a1 = ldfrag(buf1, w * 32 + 16, kk * 32, l);
            s0 = __builtin_amdgcn_mfma_f32_16x16x32_bf16(a0, bq, s0, 0, 0, 0);
            s1 = __builtin_amdgcn_mfma_f32_16x16x32_bf16(a1, bq, s1, 0, 0, 0);
        }
        const float RS = 0.08838834764831845f;
        float sv[8];
        #pragma unroll
        for (int mt = 0; mt < 2; mt++)
            #pragma unroll
            for (int j = 0; j < 4; j++){
                int kidx = mt * 16 + (hi << 2) + j;
                float x = (mt ? s1[j] : s0[j]) * RS;
                if (sidx[w * 32 + kidx] == 0) x = -INFINITY;
                sv[mt * 4 + j] = x;
            }
        float mx = sv[0];
        #pragma unroll
        for (int i = 1; i < 8; i++) mx = fmaxf(mx, sv[i]);
        mx = fmaxf(mx, __shfl_xor(mx, 16));
        mx = fmaxf(mx, __shfl_xor(mx, 32));
        float e[8], sum = 0.f;
        #pragma unroll
        for (int i = 0; i < 8; i++){ e[i] = __expf(sv[i] - mx); sum += e[i]; }
        sum += __shfl_xor(sum, 16);
        sum += __shfl_xor(sum, 32);
        float inv = 1.f / sum;
        int h = l & 15;
        char* pb = (char*)sP16 + w * 1280 + h * 80 + hi * 8;
        *(u64*)(pb)      = pack4(e[0] * inv, e[1] * inv, e[2] * inv, e[3] * inv);
        *(u64*)(pb + 32) = pack4(e[4] * inv, e[5] * inv, e[6] * inv, e[7] * inv);
    }
    __syncthreads();

    // PV via MFMA: out[h][d] = P @ V ; A = P16[h][k], B = V^T in buf0
    {
        const int l = t & 63, w = t >> 6, hi = l >> 4;
        bf16x8 pa = *(const bf16x8*)((const char*)sP16 + w * 1280 + (l & 15) * 80 + (hi << 4));
        int pid = pid0 + w;
        u32 key = ((u32)pid & 7) << 4;
        char* dst = (char*)ATT + (size_t)pid * 2048;
        #pragma unroll
        for (int nt = 0; nt < 8; nt++){
            f32x4 o;
            o = 0.f;
            bf16x8 bv = ldfrag(buf0, nt * 16, w * 32, l);
            o = __builtin_amdgcn_mfma_f32_16x16x32_bf16(pa, bv, o, 0, 0, 0);
            if (hi < 2){
                int d = nt * 16 + (l & 15);
                #pragma unroll
                for (int j = 0; j < 4; j++){
                    int h = hi * 4 + j;
                    *(u16*)(dst + h * 256 + (((u32)(d << 1)) ^ key)) = rneb(o[j]);
                }
            }
        }
    }
}

// ---------------------------------------------------------------------------
// decode: out = LN( elu(ATT@dW1+db1)@dW2+db2 + F ) * g + b
// ---------------------------------------------------------------------------
__global__ __launch_bounds__(256, 2) void decode_kernel(
    const u16* __restrict__ ATT,
    const float* __restrict__ db1, const float* __restrict__ db2,
    const float* __restrict__ F,
    const float* __restrict__ lng, const float* __restrict__ lnb,
    const char* __restrict__ ws, float* __restrict__ OUT, int n)
{
    __shared__ __align__(16) char SM[67584];
    u16* sA = (u16*)SM;              // [128][128] bf16 swizzled (staged from ATT)
    u16* sH = (u16*)(SM + 32768);    // hidden, swizzled
    float* sO = (float*)SM;          // [128][132] f32 (aliases sA/sH after L2)

    const int t = threadIdx.x;
    const int row0 = blockIdx.x * 128;
    const int l = t & 63;
    const int m0 = ((t >> 7) & 1) * 64;
    const int n0 = ((t >> 6) & 1) * 64;

    // L1: 1024 -> 128 over 8 K-chunks
    f32x4 acc[4][4];
    #pragma unroll
    for (int i = 0; i < 4; i++)
        #pragma unroll
        for (int j = 0; j < 4; j++) acc[i][j] = 0.f;
    for (int kc = 0; kc < 8; kc++){
        stage_rows((char*)sA, (const char*)ATT + (size_t)row0 * 2048 + kc * 256, 2048);
        __syncthreads();
        gemm_tileG(sA, ws + OFF_DW1T, 2048, kc * 128, acc);
        __syncthreads();
    }
    #pragma unroll
    for (int mt = 0; mt < 4; mt++)
        #pragma unroll
        for (int nt = 0; nt < 4; nt++){
            int col = n0 + nt * 16 + (l & 15);
            float bv = db1[col];
            f32x4 v;
            #pragma unroll
            for (int j = 0; j < 4; j++) v[j] = elu_f(acc[mt][nt][j] + bv);
            store_cfrag(sH, m0 + mt * 16, n0 + nt * 16, l, v);
        }
    __syncthreads();

    // L2
    f32x4 a2[4][4];
    #pragma unroll
    for (int i = 0; i < 4; i++)
        #pragma unroll
        for (int j = 0; j < 4; j++) a2[i][j] = 0.f;
    gemm_tileG(sH, ws + OFF_DW2T, 256, 0, a2);
    __syncthreads();   // sA/sH dead; sO may alias

    #pragma unroll
    for (int mt = 0; mt < 4; mt++)
        #pragma unroll
        for (int nt = 0; nt < 4; nt++){
            int col = n0 + nt * 16 + (l & 15);
            float bv = db2[col];
            int r0 = m0 + mt * 16 + ((l >> 4) << 2);
            #pragma unroll
            for (int j = 0; j < 4; j++){
                int r = r0 + j;
                int gr = row0 + r;
                float x = a2[mt][nt][j] + bv;
                if (gr < n) x += F[(size_t)gr * ND + col];
                sO[r * 132 + col] = x;
            }
        }
    __syncthreads();

    // LayerNorm: 2 threads per row
    {
        int r = t >> 1, half = t & 1;
        const float* rowp = sO + r * 132 + half * 64;
        float s = 0.f;
        #pragma unroll
        for (int i = 0; i < 16; i++){
            float4 v = ((const float4*)rowp)[i];
            s += v.x + v.y + v.z + v.w;
        }
        s += __shfl_xor(s, 1);
        float mu = s * (1.0f / 128.0f);
        float q = 0.f;
        #pragma unroll
        for (int i = 0; i < 16; i++){
            float4 v = ((const float4*)rowp)[i];
            q += (v.x - mu) * (v.x - mu) + (v.y - mu) * (v.y - mu)
               + (v.z - mu) * (v.z - mu) + (v.w - mu) * (v.w - mu);
        }
        q += __shfl_xor(q, 1);
        float rstd = rsqrtf(q * (1.0f / 128.0f) + 1e-5f);
        int gr = row0 + r;
        if (gr < n){
            #pragma unroll
            for (int i = 0; i < 16; i++){
                float4 v = ((const float4*)rowp)[i];
                int c = half * 64 + i * 4;
                float4 g4 = *(const float4*)&lng[c];
                float4 b4 = *(const float4*)&lnb[c];
                float4 ov = make_float4((v.x - mu) * rstd * g4.x + b4.x,
                                        (v.y - mu) * rstd * g4.y + b4.y,
                                        (v.z - mu) * rstd * g4.z + b4.z,
                                        (v.w - mu) * rstd * g4.w + b4.w);
                *(float4*)&OUT[(size_t)gr * ND + c] = ov;
            }
        }
    }
}

// ---------------------------------------------------------------------------
extern "C" void kernel_launch(void* const* d_in, const int* in_sizes, int n_in,
                              void* d_out, int out_size, void* d_ws, size_t ws_size,
                              hipStream_t stream)
{
    const float* F    = (const float*)d_in[0];
    const float* X    = (const float*)d_in[1];
    const float* NUV  = (const float*)d_in[2];
    const int*   TOPK = (const int*)d_in[3];
    const float* qW1  = (const float*)d_in[4];
    const float* qb1  = (const float*)d_in[5];
    const float* qW2  = (const float*)d_in[6];
    const float* qb2  = (const float*)d_in[7];
    const float* gW1  = (const float*)d_in[8];
    const float* gb1  = (const float*)d_in[9];
    const float* gW2  = (const float*)d_in[10];
    const float* gb2  = (const float*)d_in[11];
    const float* kW1  = (const float*)d_in[12];
    const float* kb1  = (const float*)d_in[13];
    const float* kW2  = (const float*)d_in[14];
    const float* kb2  = (const float*)d_in[15];
    const float* vW1  = (const float*)d_in[16];
    const float* vb1  = (const float*)d_in[17];
    const float* vW2  = (const float*)d_in[18];
    const float* vb2  = (const float*)d_in[19];
    const float* dW1  = (const float*)d_in[20];
    const float* db1  = (const float*)d_in[21];
    const float* dW2  = (const float*)d_in[22];
    const float* db2  = (const float*)d_in[23];
    const float* lng  = (const float*)d_in[24];
    const float* lnb  = (const float*)d_in[25];

    const int n = in_sizes[0] / ND;
    char* wsb = (char*)d_ws;

    PrepDesc pd;
    const float* srcs[10] = {qW1, qW2, gW1, gW2, kW1, kW2, vW1, vW2, dW1, dW2};
    u64 offs[10] = {OFF_QW1T, OFF_QW2T, OFF_GW1T, OFF_GW2T, OFF_KW1T,
                    OFF_KW2T, OFF_VW1T, OFF_VW2T, OFF_DW1T, OFF_DW2T};
    int Ns[10]   = {128, 1024, 128, 128, 128, 128, 128, 128, 128, 128};
    int Ksrc[10] = {128, 128, 12, 128, 128, 128, 128, 128, 1024, 128};
    int Kdst[10] = {128, 128, 32, 128, 128, 128, 128, 128, 1024, 128};
    for (int i = 0; i < 10; i++){
        pd.src[i] = srcs[i]; pd.dstoff[i] = offs[i];
        pd.N[i] = Ns[i]; pd.Ksrc[i] = Ksrc[i]; pd.Kdst[i] = Kdst[i];
    }
    prep_weights<<<186, 256, 0, stream>>>(pd, wsb);

    u16* Qg  = (u16*)(wsb + OFF_Q);
    u16* ATT = (u16*)(wsb + OFF_ATT);
    const int nb = (n + 127) / 128;

    qmlp_kernel<<<nb, 256, 0, stream>>>(F, qb1, qb2, wsb, Qg, n);
    attn_kernel<<<n / 4, 256, 0, stream>>>(F, X, NUV, TOPK, gb1, gb2,
                                           kb1, kb2, vb1, vb2, wsb, Qg, ATT);
    decode_kernel<<<nb, 256, 0, stream>>>(ATT, db1, db2, F, lng, lnb, wsb, (float*)d_out, n);
}